// Round 1
// 77.528 us; speedup vs baseline: 1.0034x; 1.0034x over previous
//
#include <hip/hip_runtime.h>
#include <math.h>

#define EPS2f 0.25f
#define EPS4f 0.0625f

// ---------------------------------------------------------------------------
// Kernel 1: precompute per-(ij,k) tables.
//   AB4 (float4 view)[k2*1024 + ij] = { A(2k2), B2(2k2), A(2k2+1), B2(2k2+1) }
//        A = 1/Sigma, B2 = 2*mu_t/Sigma
//   KV4 (float4 view)[ij2*64 + k]   = { K(ij_e), Vm(ij_e), K(ij_o), Vm(ij_o) }
//   C0 [ij] = sum_k ( mu_t^2/Sigma + log(Sigma) )
// Stores are bounced through LDS so the global writes are (near-)coalesced:
// the old direct AB2 store had lane stride 16 KiB = 64 transactions/wave.
// ---------------------------------------------------------------------------
__global__ __launch_bounds__(256) void precomp_kernel(
    const float* __restrict__ Mu0, const float* __restrict__ Mu1,
    const float* __restrict__ S0,  const float* __restrict__ S1,
    const float* __restrict__ tptr,
    float2* __restrict__ AB2, float2* __restrict__ KV2,
    float* __restrict__ C0)
{
    __shared__ float2 abS[4][67];   // [ij_loc][k], padded row to break conflicts
    __shared__ float2 kvS[4][64];   // [ij_loc][k]

    const int tid = threadIdx.x;
    const int k   = tid & 63;
    const int ijl = tid >> 6;                 // 0..3
    const int ij0 = blockIdx.x << 2;
    const int ij  = ij0 + ijl;
    const int i   = ij >> 5;                  // N0=32
    const int j   = ij & 31;                  // N1=32
    const float t   = *tptr;
    const float omt = 1.0f - t;

    const float s0 = S0[i * 64 + k];
    const float s1 = S1[j * 64 + k];
    const float m0 = Mu0[i * 64 + k];
    const float m1 = Mu1[j * 64 + k];

    const float ds  = sqrtf(4.0f * s0 * s1 + EPS4f);
    const float cs  = 0.5f * (ds - EPS2f);
    const float mt  = omt * m0 + t * m1;
    const float sig = omt * omt * s0 + t * t * s1
                    + 2.0f * t * omt * (cs + 0.5f * EPS2f);
    const float isig = 1.0f / sig;
    const float st = t * s1 - omt * s0 + (omt - t) * cs - EPS2f * t;
    const float kk = st * isig;
    const float v  = m1 - m0;

    abS[ijl][k] = make_float2(isig, 2.0f * mt * isig);
    kvS[ijl][k] = make_float2(kk, v - kk * mt);

    float c = mt * mt * isig + __logf(sig);
    #pragma unroll
    for (int off = 32; off >= 1; off >>= 1)
        c += __shfl_xor(c, off, 64);
    if (k == 0) C0[ij] = c;

    __syncthreads();

    // AB store, store-linear-ish mapping: tid = k2*8 + ijl2*2 + par
    // -> per wave: 8 contiguous 64B chunks (was 64 scattered 8B stores).
    {
        const int k2   = tid >> 3;            // 0..31
        const int ijl2 = (tid >> 1) & 3;
        const int par  = tid & 1;
        AB2[(k2 << 11) + ((ij0 + ijl2) << 1) + par] = abS[ijl2][2 * k2 + par];
    }
    // KV store: fully linear in tid (bijection with original layout:
    // slot = ((ij>>1)<<7)+(k<<1)+(ij&1) with ij_loc = 2*(tid>>7)+(tid&1)).
    {
        const int pr  = tid >> 7;             // 0..1
        const int k6  = (tid >> 1) & 63;
        const int par = tid & 1;
        KV2[(blockIdx.x << 8) + tid] = kvS[(pr << 1) + par][k6];
    }
}

// ---------------------------------------------------------------------------
// Kernel 2: main. Block = 4 batch rows x all 1024 ij. 1024 threads = 16 waves.
// Both phases run an explicit 8-deep rotating VMEM pipeline (static indices
// via full unroll) so ~8 L2 loads stay in flight per wave; under the 128-VGPR
// cap the compiler's own unroll serialized the load stream and each wave paid
// L2-hit latency (~200-300 cyc) per small load group -> per-wave-critical-path
// bound at 16 waves/CU.
// ---------------------------------------------------------------------------
__global__ __launch_bounds__(1024) void gmm_main_kernel(
    const float* __restrict__ X,   const float* __restrict__ Lam,
    const float* __restrict__ C0,
    const float4* __restrict__ AB4, const float4* __restrict__ KV4,
    float* __restrict__ out)
{
    __shared__ float4 Xs4[64];           // [k] = x for bb=0..3 (bcast b128)
    __shared__ float4 Wl4[1024 * 2];     // [ij][2]: slot 0 = W for bb=0..3
    __shared__ float  red[16 * 64 * 5];  // [w][k][bb], stride 5: conflict-free
    __shared__ float  XsT[4 * 64];       // [bb][k]
    __shared__ float  denp[16 * 4];      // per-wave per-bb den partials

    const int tid  = threadIdx.x;
    const int lane = tid & 63;
    const int w    = tid >> 6;           // 0..15
    const int b0   = blockIdx.x << 2;

    if (tid < 256) {
        const int bb = tid >> 6, k = tid & 63;
        const float xv = X[(b0 + bb) * 64 + k];
        ((float*)&Xs4[k])[bb] = xv;
        XsT[bb * 64 + k] = xv;
    }

    // ---- Phase A: one ij per thread ----
    const int ij = tid;
    const float4* __restrict__ abp = AB4 + ij;   // stride 1024 float4 per k2
    const float c0 = C0[ij];
    const float lm = Lam[ij];

    // 8-deep prefetch issued BEFORE the barrier: latency hides under staging.
    float4 ab[8];
    #pragma unroll
    for (int g = 0; g < 8; ++g) ab[g] = abp[g << 10];

    __syncthreads();

    float qa = 0.f, qb = 0.f, qc = 0.f, qd = 0.f;
    #pragma unroll
    for (int k2 = 0; k2 < 32; ++k2) {
        const float4 a = ab[k2 & 7];
        if (k2 + 8 < 32) ab[k2 & 7] = abp[(k2 + 8) << 10];
        const float4 x0 = Xs4[2 * k2];            // LDS broadcast
        const float4 x1 = Xs4[2 * k2 + 1];
        qa = fmaf(fmaf(a.x, x0.x, -a.y), x0.x, qa);
        qb = fmaf(fmaf(a.x, x0.y, -a.y), x0.y, qb);
        qc = fmaf(fmaf(a.x, x0.z, -a.y), x0.z, qc);
        qd = fmaf(fmaf(a.x, x0.w, -a.y), x0.w, qd);
        qa = fmaf(fmaf(a.z, x1.x, -a.w), x1.x, qa);
        qb = fmaf(fmaf(a.z, x1.y, -a.w), x1.y, qb);
        qc = fmaf(fmaf(a.z, x1.z, -a.w), x1.z, qc);
        qd = fmaf(fmaf(a.z, x1.w, -a.w), x1.w, qd);
    }

    #define WCALC(q) (__expf(fminf(fmaxf(-0.5f * ((q) + c0), -50.f), 50.f)) * lm)
    float4 wv4;
    wv4.x = WCALC(qa); wv4.y = WCALC(qb); wv4.z = WCALC(qc); wv4.w = WCALC(qd);
    #undef WCALC
    Wl4[ij * 2] = wv4;                   // aligned 16B row -> ds_read_b128 later

    // ---- Phase B prologue: issue the first 8 KV loads NOW so they fly
    // under the den shuffle-reduction (addresses independent of W). ----
    const int p0 = w << 5;               // first pair index of this wave
    float4 kvb[8];
    #pragma unroll
    for (int q = 0; q < 8; ++q) kvb[q] = KV4[((p0 + q) << 6) + lane];
    const float xk0 = XsT[0 * 64 + lane], xk1 = XsT[1 * 64 + lane];
    const float xk2 = XsT[2 * 64 + lane], xk3 = XsT[3 * 64 + lane];

    float d0 = wv4.x, d1 = wv4.y, d2 = wv4.z, d3 = wv4.w;
    #pragma unroll
    for (int off = 32; off >= 1; off >>= 1) {
        d0 += __shfl_xor(d0, off, 64);
        d1 += __shfl_xor(d1, off, 64);
        d2 += __shfl_xor(d2, off, 64);
        d3 += __shfl_xor(d3, off, 64);
    }
    if (lane == 0) {
        denp[w * 4 + 0] = d0; denp[w * 4 + 1] = d1;
        denp[w * 4 + 2] = d2; denp[w * 4 + 3] = d3;
    }

    // ---- Phase B: wave w, 32 ij-pairs, lane = k ----
    // (Wl rows [64w, 64w+64) written by this same wave: no barrier needed.)
    float n0 = 0.f, n1 = 0.f, n2 = 0.f, n3 = 0.f;
    #pragma unroll
    for (int p = 0; p < 32; ++p) {
        const float4 kv = kvb[p & 7];
        if (p + 8 < 32) kvb[p & 7] = KV4[((p0 + p + 8) << 6) + lane];
        const float4 we = Wl4[(p0 + p) * 4];           // ij_e = 2*(p0+p)
        const float4 wo = Wl4[(p0 + p) * 4 + 2];       // ij_o
        float u;
        u = fmaf(kv.x, xk0, kv.y); n0 = fmaf(we.x, u, n0);
        u = fmaf(kv.x, xk1, kv.y); n1 = fmaf(we.y, u, n1);
        u = fmaf(kv.x, xk2, kv.y); n2 = fmaf(we.z, u, n2);
        u = fmaf(kv.x, xk3, kv.y); n3 = fmaf(we.w, u, n3);
        u = fmaf(kv.z, xk0, kv.w); n0 = fmaf(wo.x, u, n0);
        u = fmaf(kv.z, xk1, kv.w); n1 = fmaf(wo.y, u, n1);
        u = fmaf(kv.z, xk2, kv.w); n2 = fmaf(wo.z, u, n2);
        u = fmaf(kv.z, xk3, kv.w); n3 = fmaf(wo.w, u, n3);
    }
    {
        float* r = &red[(w * 64 + lane) * 5];
        r[0] = n0; r[1] = n1; r[2] = n2; r[3] = n3;
    }
    __syncthreads();

    // ---- Epilogue ----
    if (tid < 256) {
        const int bb = tid >> 6, k = tid & 63;   // bb wave-uniform
        float s = 0.f, d = 0.f;
        #pragma unroll
        for (int ww = 0; ww < 16; ++ww) {
            s += red[(ww * 64 + k) * 5 + bb];
            d += denp[ww * 4 + bb];
        }
        out[(b0 + bb) * 64 + k] = s / d;
    }
}

extern "C" void kernel_launch(void* const* d_in, const int* in_sizes, int n_in,
                              void* d_out, int out_size, void* d_ws, size_t ws_size,
                              hipStream_t stream) {
    const float* X   = (const float*)d_in[0];
    const float* Mu0 = (const float*)d_in[1];
    const float* Mu1 = (const float*)d_in[2];
    const float* S0  = (const float*)d_in[3];
    const float* S1  = (const float*)d_in[4];
    const float* Lam = (const float*)d_in[5];
    const float* t   = (const float*)d_in[6];
    float* out = (float*)d_out;

    char* ws = (char*)d_ws;
    float2* AB2 = (float2*)(ws);                  // 512 KiB
    float2* KV2 = (float2*)(ws + (512 << 10));    // 512 KiB
    float*  C0  = (float*)(ws + (1024 << 10));    // 4 KiB

    precomp_kernel<<<256, 256, 0, stream>>>(Mu0, Mu1, S0, S1, t, AB2, KV2, C0);
    gmm_main_kernel<<<256, 1024, 0, stream>>>(X, Lam, C0,
                                              (const float4*)AB2,
                                              (const float4*)KV2, out);
}